// Round 1
// baseline (627.006 us; speedup 1.0000x reference)
//
#include <hip/hip_runtime.h>

#define NB 8
#define NC 256
#define ND 32
#define NN 16384
#define EPSF 1e-6f

__device__ __forceinline__ float softplusf(float v) {
    // stable log1p(exp(v))
    return fmaxf(v, 0.0f) + log1pf(__expf(-fabsf(v)));
}

// ---------------------------------------------------------------------------
// Kernel T: transpose wq [32][256] -> wqT [256][32] (once, tiny).
// ---------------------------------------------------------------------------
__global__ __launch_bounds__(256) void kT(const float* __restrict__ wq,
                                          float* __restrict__ wqT)
{
    int idx = blockIdx.x * 256 + threadIdx.x;   // [0, 8192)
    int c = idx >> 5, m = idx & 31;
    wqT[idx] = wq[m * 256 + c];
}

// ---------------------------------------------------------------------------
// Kernel A: per (b, 256-col tile): K = softplus(wk@x + bk); accumulate
//   KX[m][e] = sum_n K[m][n]*x[e][n]  (partials per block) and Ksum[m].
// block = 256 threads, grid = 8*64 = 512. LDS ~71 KB -> 2 blocks/CU.
// ---------------------------------------------------------------------------
__global__ __launch_bounds__(256) void kA(
    const float* __restrict__ x, const float* __restrict__ wk,
    const float* __restrict__ bk, float* __restrict__ part,
    float* __restrict__ kxf, float* __restrict__ ksum, int use_part)
{
    __shared__ __align__(16) float xsT[32 * 258];  // [j][c], pad 2: b64-aligned, <=2-way banks
    __shared__ __align__(16) float wkM[32 * 260];  // [m][c], pad 4: b128-aligned
    __shared__ __align__(16) float Ks [32 * 36];   // [j][m], pad 4: b128-aligned

    const int t    = threadIdx.x;
    const int b    = blockIdx.x >> 6;
    const int tile = blockIdx.x & 63;
    const int n0   = tile << 8;                    // 256 columns per block
    const float* xb = x + (size_t)b * NC * NN;

    // stage wk as wkM[m][c] (coalesced read)
    #pragma unroll
    for (int i = 0; i < 32; ++i) {
        int f = t + (i << 8);
        wkM[(f >> 8) * 260 + (f & 255)] = wk[f];
    }

    const int jA  = t & 31;          // K-compute: column j
    const int m0A = (t >> 5) << 2;   // K-compute: 4 m's
    const int m0X = (t >> 6) << 3;   // KX: 8 m's
    const int eX  = t & 63;          // KX: e base (4 e's: eX + 64k)

    float bkr[4];
    #pragma unroll
    for (int r = 0; r < 4; ++r) bkr[r] = bk[m0A + r];

    float acc[8][4];
    #pragma unroll
    for (int a = 0; a < 8; ++a)
        #pragma unroll
        for (int kk = 0; kk < 4; ++kk) acc[a][kk] = 0.0f;
    float ksacc[4] = {0.f, 0.f, 0.f, 0.f};

    for (int st = 0; st < 8; ++st) {
        const int n1 = n0 + (st << 5);
        __syncthreads();  // xsT free from previous iter's KX readers (covers wkM on st=0)
        // stage 256x32 x sub-tile, transposed: xsT[j][c]
        #pragma unroll
        for (int i = 0; i < 32; ++i) {
            int f = t + (i << 8);
            int c = f >> 5, j = f & 31;
            xsT[j * 258 + c] = xb[c * NN + n1 + j];
        }
        __syncthreads();

        // --- K compute: K[m0A..+3][jA] ---
        float kacc[4] = {0.f, 0.f, 0.f, 0.f};
        #pragma unroll 4
        for (int c = 0; c < 256; c += 4) {
            float2 xa = *(const float2*)&xsT[jA * 258 + c];
            float2 xc = *(const float2*)&xsT[jA * 258 + c + 2];
            #pragma unroll
            for (int r = 0; r < 4; ++r) {
                float4 w = *(const float4*)&wkM[(m0A + r) * 260 + c];
                kacc[r] = fmaf(xa.x, w.x, kacc[r]);
                kacc[r] = fmaf(xa.y, w.y, kacc[r]);
                kacc[r] = fmaf(xc.x, w.z, kacc[r]);
                kacc[r] = fmaf(xc.y, w.w, kacc[r]);
            }
        }
        #pragma unroll
        for (int r = 0; r < 4; ++r) {
            float kv_ = softplusf(kacc[r] + bkr[r]);
            Ks[jA * 36 + m0A + r] = kv_;
            ksacc[r] += kv_;
        }
        __syncthreads();

        // --- KX accumulate: acc[a][kk] += K[m0X+a][j] * x[eX+64kk][j] ---
        #pragma unroll 2
        for (int j = 0; j < 32; ++j) {
            const float* kp = &Ks[j * 36 + m0X];
            float4 ka = *(const float4*)kp;        // wave-uniform broadcast
            float4 kb = *(const float4*)(kp + 4);
            const float km[8] = {ka.x, ka.y, ka.z, ka.w, kb.x, kb.y, kb.z, kb.w};
            float xv[4];
            #pragma unroll
            for (int kk = 0; kk < 4; ++kk) xv[kk] = xsT[j * 258 + eX + (kk << 6)];
            #pragma unroll
            for (int a = 0; a < 8; ++a)
                #pragma unroll
                for (int kk = 0; kk < 4; ++kk)
                    acc[a][kk] = fmaf(km[a], xv[kk], acc[a][kk]);
        }
    }

    // Ksum: reduce over jA (lanes 0..31 within each 32-lane slot group)
    #pragma unroll
    for (int r = 0; r < 4; ++r) {
        float v = ksacc[r];
        for (int o = 16; o; o >>= 1) v += __shfl_down(v, o, 32);
        if (jA == 0) atomicAdd(&ksum[b * 32 + m0A + r], v);
    }

    // KX epilogue
    if (use_part) {
        float* dst = part + (size_t)blockIdx.x * 8192;
        #pragma unroll
        for (int a = 0; a < 8; ++a)
            #pragma unroll
            for (int kk = 0; kk < 4; ++kk)
                dst[(m0X + a) * 256 + eX + (kk << 6)] = acc[a][kk];
    } else {
        float* dst = kxf + (size_t)b * 8192;
        #pragma unroll
        for (int a = 0; a < 8; ++a)
            #pragma unroll
            for (int kk = 0; kk < 4; ++kk)
                atomicAdd(&dst[(m0X + a) * 256 + eX + (kk << 6)], acc[a][kk]);
    }
}

// ---------------------------------------------------------------------------
// Kernel R: reduce 64 tile-partials per batch -> KX final. grid 256 x 256.
// ---------------------------------------------------------------------------
__global__ __launch_bounds__(256) void kR(const float* __restrict__ part,
                                          float* __restrict__ kxf)
{
    int idx = blockIdx.x * 256 + threadIdx.x;   // [0, 8*8192)
    int b = idx >> 13, f = idx & 8191;
    float s = 0.f;
    #pragma unroll 8
    for (int tl = 0; tl < 64; ++tl)
        s += part[(size_t)(b * 64 + tl) * 8192 + f];
    kxf[idx] = s;
}

// ---------------------------------------------------------------------------
// Kernel B: KV[m][c] = sum_e KX[m][e]*wv[c][e] + bv[c]*Ksum[m].
// grid 64 = 8b x 8 c-groups of 32; 256 threads. Writes kvT[c][m] (transposed)
// so kC can consume KV with wave-uniform scalar loads.
// ---------------------------------------------------------------------------
__global__ __launch_bounds__(256) void kB(
    const float* __restrict__ kxf, const float* __restrict__ ksum,
    const float* __restrict__ wv, const float* __restrict__ bv,
    float* __restrict__ kvT)
{
    __shared__ float wvT[256 * 33];  // [e][cl]
    __shared__ float kxs[32 * 257];  // [m][e]

    const int t  = threadIdx.x;
    const int b  = blockIdx.x >> 3;
    const int c0 = (blockIdx.x & 7) << 5;

    #pragma unroll
    for (int i = 0; i < 32; ++i) {
        int f = t + (i << 8);
        int r = f >> 8, e = f & 255;
        wvT[e * 33 + r]  = wv[(size_t)(c0 + r) * 256 + e];
        kxs[r * 257 + e] = kxf[b * 8192 + f];
    }
    __syncthreads();

    const int cl = t & 31, mq = t >> 5;
    float a0 = 0.f, a1 = 0.f, a2 = 0.f, a3 = 0.f;
    for (int e = 0; e < 256; ++e) {
        float wvv = wvT[e * 33 + cl];
        a0 = fmaf(kxs[(mq     ) * 257 + e], wvv, a0);
        a1 = fmaf(kxs[(mq +  8) * 257 + e], wvv, a1);
        a2 = fmaf(kxs[(mq + 16) * 257 + e], wvv, a2);
        a3 = fmaf(kxs[(mq + 24) * 257 + e], wvv, a3);
    }
    const int c = c0 + cl;
    const float bvc = bv[c];
    const float* ks = ksum + b * 32;
    float* kvb = kvT + (size_t)b * 8192;
    kvb[c * 32 + (mq     )] = a0 + bvc * ks[mq     ];
    kvb[c * 32 + (mq +  8)] = a1 + bvc * ks[mq +  8];
    kvb[c * 32 + (mq + 16)] = a2 + bvc * ks[mq + 16];
    kvb[c * 32 + (mq + 24)] = a3 + bvc * ks[mq + 24];
}

// ---------------------------------------------------------------------------
// Kernel C (v2): per-column register formulation.
// Each block: 64 columns x all 256 channels. 256 threads.
// Phase Q: wave w owns c-slice [64w,64w+64); lane = column. q-partials in
//   registers, wq read as wave-uniform scalar loads (SGPR operands), x from
//   a conflict-free row-read of the LDS tile. Partials combined across the
//   4 waves via ds_add_f32 into Qs[col][m] (stride 33 -> conflict-free).
// Phase S: softplus(Qs + bq) in place.
// Phase O: thread (j = t&63, cg = t>>6) computes out[c][n1+j] for the 64
//   channels c in its cg-group; KV read as wave-uniform scalar loads,
//   residual x from LDS. Only xs + Qs in LDS: 74 KB -> 2 blocks/CU.
// grid = 8 * 256 = 2048.
// ---------------------------------------------------------------------------
__global__ __launch_bounds__(256) void kC(
    const float* __restrict__ x, const float* __restrict__ wqT,
    const float* __restrict__ bq, const float* __restrict__ kvT,
    const float* __restrict__ ksum, const float* __restrict__ gamma,
    float* __restrict__ out)
{
    __shared__ __align__(16) float xs[256 * 64];  // [c][j], stride 64: row reads conflict-free
    __shared__ float Qs[64 * 33];                 // [col][m], stride 33: (col+m)%32 banks

    const int t    = threadIdx.x;
    const int b    = blockIdx.x >> 8;             // 256 tiles per batch
    const int tile = blockIdx.x & 255;
    const int n1   = tile << 6;
    const float* __restrict__ xb  = x   + (size_t)b * NC * NN;
    const float* __restrict__ kvb = kvT + (size_t)b * 8192;

    // zero Q accumulator tile
    #pragma unroll
    for (int i = 0; i < 9; ++i) {
        int f = t + (i << 8);
        if (f < 64 * 33) Qs[f] = 0.0f;
    }

    // stage xs[c][j] <- x[c][n1+j], float4 (16B/lane, fully coalesced)
    #pragma unroll
    for (int i = 0; i < 16; ++i) {
        int q4 = t + (i << 8);                    // [0,4096): 16 float4 per row
        int c = q4 >> 4, jq = q4 & 15;
        *(float4*)&xs[c * 64 + (jq << 2)] =
            *(const float4*)&xb[(size_t)c * NN + n1 + (jq << 2)];
    }
    __syncthreads();

    const int lane = t & 63;
    const int w    = t >> 6;

    // --- Phase Q: partial Q[m][lane] over c-slice w ---
    {
        float qp[32];
        #pragma unroll
        for (int m = 0; m < 32; ++m) qp[m] = 0.0f;
        const int cbase = w << 6;
        #pragma unroll 2
        for (int i = 0; i < 64; ++i) {
            const int c = cbase + i;
            const float xv = xs[c * 64 + lane];              // row read, conflict-free
            const float* __restrict__ wr = wqT + c * 32;     // wave-uniform -> s_load
            #pragma unroll
            for (int m = 0; m < 32; ++m)
                qp[m] = fmaf(wr[m], xv, qp[m]);
        }
        #pragma unroll
        for (int m = 0; m < 32; ++m)
            atomicAdd(&Qs[lane * 33 + m], qp[m]);            // ds_add_f32
    }
    __syncthreads();

    // --- Phase S: softplus(. + bq) in place; thread owns (col, 8 m's) ---
    {
        const int col = t & 63, ms = t >> 6;
        #pragma unroll
        for (int r = 0; r < 8; ++r) {
            const int m = (ms << 3) + r;                     // wave-uniform m
            Qs[col * 33 + m] = softplusf(Qs[col * 33 + m] + bq[m]);
        }
    }
    __syncthreads();

    // --- Phase O: out[c][n1+j] for c in cg-slice, j = lane ---
    {
        const int j = lane, cg = w;
        float q[32];
        #pragma unroll
        for (int m = 0; m < 32; ++m) q[m] = Qs[j * 33 + m];
        const float* __restrict__ ksb = ksum + (b << 5);     // wave-uniform
        float den = 0.0f;
        #pragma unroll
        for (int m = 0; m < 32; ++m) den = fmaf(q[m], ksb[m] + EPSF, den);
        const float nrm = gamma[0] / den;

        const int cbase = cg << 6;
        float* __restrict__ ob = out + (size_t)b * NC * NN + n1 + j;
        #pragma unroll 2
        for (int i = 0; i < 64; ++i) {
            const int c = cbase + i;
            const float* __restrict__ kr = kvb + c * 32;     // wave-uniform -> s_load
            float s = 0.0f;
            #pragma unroll
            for (int m = 0; m < 32; ++m)
                s = fmaf(kr[m], q[m], s);
            ob[(size_t)c * NN] = xs[c * 64 + j] + nrm * s;   // coalesced 256B store/row
        }
    }
}

// ---------------------------------------------------------------------------
extern "C" void kernel_launch(void* const* d_in, const int* in_sizes, int n_in,
                              void* d_out, int out_size, void* d_ws, size_t ws_size,
                              hipStream_t stream)
{
    (void)in_sizes; (void)n_in; (void)out_size;
    const float* x     = (const float*)d_in[0];
    const float* wq    = (const float*)d_in[1];
    const float* bq    = (const float*)d_in[2];
    const float* wk    = (const float*)d_in[3];
    const float* bk    = (const float*)d_in[4];
    const float* wv    = (const float*)d_in[5];
    const float* bv    = (const float*)d_in[6];
    const float* gamma = (const float*)d_in[7];
    float* out = (float*)d_out;

    char* ws = (char*)d_ws;
    float* kxf  = (float*)(ws);              // 8*8192 floats   = 262144 B
    float* ksum = (float*)(ws + 262144);     // 256 floats      = 1024 B
    float* kvT  = (float*)(ws + 263168);     // 8*8192 floats   = 262144 B
    float* wqT  = (float*)(ws + 525312);     // 8192 floats     = 32768 B
    float* part = (float*)(ws + 558080);     // 512*8192 floats = 16 MB (optional)
    const size_t need_part = 558080ull + 512ull * 8192ull * 4ull;
    const int use_part = (ws_size >= need_part) ? 1 : 0;

    hipMemsetAsync(ksum, 0, 1024, stream);
    if (!use_part) hipMemsetAsync(kxf, 0, 262144, stream);

    kT<<<dim3(32), dim3(256), 0, stream>>>(wq, wqT);
    kA<<<dim3(512), dim3(256), 0, stream>>>(x, wk, bk, part, kxf, ksum, use_part);
    if (use_part) kR<<<dim3(256), dim3(256), 0, stream>>>(part, kxf);
    kB<<<dim3(64), dim3(256), 0, stream>>>(kxf, ksum, wv, bv, kvT);
    kC<<<dim3(2048), dim3(256), 0, stream>>>(x, wqT, bq, kvT, ksum, gamma, out);
}

// Round 3
// 439.718 us; speedup vs baseline: 1.4259x; 1.4259x over previous
//
#include <hip/hip_runtime.h>

#define NB 8
#define NC 256
#define ND 32
#define NN 16384
#define EPSF 1e-6f

__device__ __forceinline__ float softplusf(float v) {
    // stable log1p(exp(v))
    return fmaxf(v, 0.0f) + log1pf(__expf(-fabsf(v)));
}

// ---------------------------------------------------------------------------
// Kernel A: per (b, 256-col tile): K = softplus(wk@x + bk); accumulate
//   KX[m][e] = sum_n K[m][n]*x[e][n]  (partials per block) and Ksum[m].
// block = 256 threads, grid = 8*64 = 512. LDS ~71 KB -> 2 blocks/CU.
// ---------------------------------------------------------------------------
__global__ __launch_bounds__(256) void kA(
    const float* __restrict__ x, const float* __restrict__ wk,
    const float* __restrict__ bk, float* __restrict__ part,
    float* __restrict__ kxf, float* __restrict__ ksum, int use_part)
{
    __shared__ __align__(16) float xsT[32 * 258];  // [j][c], pad 2: b64-aligned, <=2-way banks
    __shared__ __align__(16) float wkM[32 * 260];  // [m][c], pad 4: b128-aligned
    __shared__ __align__(16) float Ks [32 * 36];   // [j][m], pad 4: b128-aligned

    const int t    = threadIdx.x;
    const int b    = blockIdx.x >> 6;
    const int tile = blockIdx.x & 63;
    const int n0   = tile << 8;                    // 256 columns per block
    const float* xb = x + (size_t)b * NC * NN;

    // stage wk as wkM[m][c] (coalesced read)
    #pragma unroll
    for (int i = 0; i < 32; ++i) {
        int f = t + (i << 8);
        wkM[(f >> 8) * 260 + (f & 255)] = wk[f];
    }

    const int jA  = t & 31;          // K-compute: column j
    const int m0A = (t >> 5) << 2;   // K-compute: 4 m's
    const int m0X = (t >> 6) << 3;   // KX: 8 m's
    const int eX  = t & 63;          // KX: e base (4 e's: eX + 64k)

    float bkr[4];
    #pragma unroll
    for (int r = 0; r < 4; ++r) bkr[r] = bk[m0A + r];

    float acc[8][4];
    #pragma unroll
    for (int a = 0; a < 8; ++a)
        #pragma unroll
        for (int kk = 0; kk < 4; ++kk) acc[a][kk] = 0.0f;
    float ksacc[4] = {0.f, 0.f, 0.f, 0.f};

    for (int st = 0; st < 8; ++st) {
        const int n1 = n0 + (st << 5);
        __syncthreads();  // xsT free from previous iter's KX readers (covers wkM on st=0)
        // stage 256x32 x sub-tile, transposed: xsT[j][c]
        #pragma unroll
        for (int i = 0; i < 32; ++i) {
            int f = t + (i << 8);
            int c = f >> 5, j = f & 31;
            xsT[j * 258 + c] = xb[c * NN + n1 + j];
        }
        __syncthreads();

        // --- K compute: K[m0A..+3][jA] ---
        float kacc[4] = {0.f, 0.f, 0.f, 0.f};
        #pragma unroll 4
        for (int c = 0; c < 256; c += 4) {
            float2 xa = *(const float2*)&xsT[jA * 258 + c];
            float2 xc = *(const float2*)&xsT[jA * 258 + c + 2];
            #pragma unroll
            for (int r = 0; r < 4; ++r) {
                float4 w = *(const float4*)&wkM[(m0A + r) * 260 + c];
                kacc[r] = fmaf(xa.x, w.x, kacc[r]);
                kacc[r] = fmaf(xa.y, w.y, kacc[r]);
                kacc[r] = fmaf(xc.x, w.z, kacc[r]);
                kacc[r] = fmaf(xc.y, w.w, kacc[r]);
            }
        }
        #pragma unroll
        for (int r = 0; r < 4; ++r) {
            float kv_ = softplusf(kacc[r] + bkr[r]);
            Ks[jA * 36 + m0A + r] = kv_;
            ksacc[r] += kv_;
        }
        __syncthreads();

        // --- KX accumulate: acc[a][kk] += K[m0X+a][j] * x[eX+64kk][j] ---
        #pragma unroll 2
        for (int j = 0; j < 32; ++j) {
            const float* kp = &Ks[j * 36 + m0X];
            float4 ka = *(const float4*)kp;        // wave-uniform broadcast
            float4 kb = *(const float4*)(kp + 4);
            const float km[8] = {ka.x, ka.y, ka.z, ka.w, kb.x, kb.y, kb.z, kb.w};
            float xv[4];
            #pragma unroll
            for (int kk = 0; kk < 4; ++kk) xv[kk] = xsT[j * 258 + eX + (kk << 6)];
            #pragma unroll
            for (int a = 0; a < 8; ++a)
                #pragma unroll
                for (int kk = 0; kk < 4; ++kk)
                    acc[a][kk] = fmaf(km[a], xv[kk], acc[a][kk]);
        }
    }

    // Ksum: reduce over jA (lanes 0..31 within each 32-lane slot group)
    #pragma unroll
    for (int r = 0; r < 4; ++r) {
        float v = ksacc[r];
        for (int o = 16; o; o >>= 1) v += __shfl_down(v, o, 32);
        if (jA == 0) atomicAdd(&ksum[b * 32 + m0A + r], v);
    }

    // KX epilogue
    if (use_part) {
        float* dst = part + (size_t)blockIdx.x * 8192;
        #pragma unroll
        for (int a = 0; a < 8; ++a)
            #pragma unroll
            for (int kk = 0; kk < 4; ++kk)
                dst[(m0X + a) * 256 + eX + (kk << 6)] = acc[a][kk];
    } else {
        float* dst = kxf + (size_t)b * 8192;
        #pragma unroll
        for (int a = 0; a < 8; ++a)
            #pragma unroll
            for (int kk = 0; kk < 4; ++kk)
                atomicAdd(&dst[(m0X + a) * 256 + eX + (kk << 6)], acc[a][kk]);
    }
}

// ---------------------------------------------------------------------------
// Kernel R: reduce 64 tile-partials per batch -> KX final. grid 256 x 256.
// ---------------------------------------------------------------------------
__global__ __launch_bounds__(256) void kR(const float* __restrict__ part,
                                          float* __restrict__ kxf)
{
    int idx = blockIdx.x * 256 + threadIdx.x;   // [0, 8*8192)
    int b = idx >> 13, f = idx & 8191;
    float s = 0.f;
    #pragma unroll 8
    for (int tl = 0; tl < 64; ++tl)
        s += part[(size_t)(b * 64 + tl) * 8192 + f];
    kxf[idx] = s;
}

// ---------------------------------------------------------------------------
// Kernel B: KV[m][c] = sum_e KX[m][e]*wv[c][e] + bv[c]*Ksum[m].
// grid 64 = 8b x 8 c-groups of 32; 256 threads. kv layout [m][c].
// ---------------------------------------------------------------------------
__global__ __launch_bounds__(256) void kB(
    const float* __restrict__ kxf, const float* __restrict__ ksum,
    const float* __restrict__ wv, const float* __restrict__ bv,
    float* __restrict__ kv)
{
    __shared__ float wvT[256 * 33];  // [e][cl]
    __shared__ float kxs[32 * 257];  // [m][e]

    const int t  = threadIdx.x;
    const int b  = blockIdx.x >> 3;
    const int c0 = (blockIdx.x & 7) << 5;

    #pragma unroll
    for (int i = 0; i < 32; ++i) {
        int f = t + (i << 8);
        int r = f >> 8, e = f & 255;
        wvT[e * 33 + r]  = wv[(size_t)(c0 + r) * 256 + e];
        kxs[r * 257 + e] = kxf[b * 8192 + f];
    }
    __syncthreads();

    const int cl = t & 31, mq = t >> 5;
    float a0 = 0.f, a1 = 0.f, a2 = 0.f, a3 = 0.f;
    for (int e = 0; e < 256; ++e) {
        float wvv = wvT[e * 33 + cl];
        a0 = fmaf(kxs[(mq     ) * 257 + e], wvv, a0);
        a1 = fmaf(kxs[(mq +  8) * 257 + e], wvv, a1);
        a2 = fmaf(kxs[(mq + 16) * 257 + e], wvv, a2);
        a3 = fmaf(kxs[(mq + 24) * 257 + e], wvv, a3);
    }
    const int c = c0 + cl;
    const float bvc = bv[c];
    const float* ks = ksum + b * 32;
    float* kvb = kv + (size_t)b * 8192;
    kvb[(mq     ) * 256 + c] = a0 + bvc * ks[mq     ];
    kvb[(mq +  8) * 256 + c] = a1 + bvc * ks[mq +  8];
    kvb[(mq + 16) * 256 + c] = a2 + bvc * ks[mq + 16];
    kvb[(mq + 24) * 256 + c] = a3 + bvc * ks[mq + 24];
}

// ---------------------------------------------------------------------------
// Kernel Q: Qhat[m][n] = gamma * softplus(wq@x + bq) / den[n],
//   den[n] = sum_m Q[m][n]*(Ksum[m]+EPS).
// Clone of kA's K-compute structure; Q values stay in registers; den via
// 32-float LDS atomic. LDS = 66.5 KB -> 2 blocks/CU.
// grid = 8*64 = 512, 256 threads.
// ---------------------------------------------------------------------------
__global__ __launch_bounds__(256) void kQ(
    const float* __restrict__ x, const float* __restrict__ wq,
    const float* __restrict__ bq, const float* __restrict__ ksum,
    const float* __restrict__ gamma, float* __restrict__ qhat)
{
    __shared__ __align__(16) float xsT[32 * 258];  // [j][c]
    __shared__ __align__(16) float wqM[32 * 260];  // [m][c]
    __shared__ float den_s[32];

    const int t    = threadIdx.x;
    const int b    = blockIdx.x >> 6;
    const int tile = blockIdx.x & 63;
    const int n0   = tile << 8;
    const float* xb = x + (size_t)b * NC * NN;
    const float g = gamma[0];

    #pragma unroll
    for (int i = 0; i < 32; ++i) {
        int f = t + (i << 8);
        wqM[(f >> 8) * 260 + (f & 255)] = wq[f];
    }

    const int jA  = t & 31;
    const int m0A = (t >> 5) << 2;

    float bqr[4], ksr[4];
    #pragma unroll
    for (int r = 0; r < 4; ++r) {
        bqr[r] = bq[m0A + r];
        ksr[r] = ksum[b * 32 + m0A + r] + EPSF;
    }

    for (int st = 0; st < 8; ++st) {
        const int n1 = n0 + (st << 5);
        __syncthreads();  // xsT free; den_s reads of prev iter done
        #pragma unroll
        for (int i = 0; i < 32; ++i) {
            int f = t + (i << 8);
            int c = f >> 5, j = f & 31;
            xsT[j * 258 + c] = xb[c * NN + n1 + j];
        }
        if (t < 32) den_s[t] = 0.0f;
        __syncthreads();

        // --- Q compute: Q[m0A..+3][jA], stays in registers ---
        float kacc[4] = {0.f, 0.f, 0.f, 0.f};
        #pragma unroll 4
        for (int c = 0; c < 256; c += 4) {
            float2 xa = *(const float2*)&xsT[jA * 258 + c];
            float2 xc = *(const float2*)&xsT[jA * 258 + c + 2];
            #pragma unroll
            for (int r = 0; r < 4; ++r) {
                float4 w = *(const float4*)&wqM[(m0A + r) * 260 + c];
                kacc[r] = fmaf(xa.x, w.x, kacc[r]);
                kacc[r] = fmaf(xa.y, w.y, kacc[r]);
                kacc[r] = fmaf(xc.x, w.z, kacc[r]);
                kacc[r] = fmaf(xc.y, w.w, kacc[r]);
            }
        }
        float qv[4];
        float pd = 0.0f;
        #pragma unroll
        for (int r = 0; r < 4; ++r) {
            qv[r] = softplusf(kacc[r] + bqr[r]);
            pd = fmaf(qv[r], ksr[r], pd);
        }
        atomicAdd(&den_s[jA], pd);   // ds_add_f32, 8 adders per column
        __syncthreads();

        const float nrm = g / den_s[jA];
        #pragma unroll
        for (int r = 0; r < 4; ++r)
            qhat[(size_t)(b * 32 + m0A + r) * NN + n1 + jA] = qv[r] * nrm;
    }
}

// ---------------------------------------------------------------------------
// Kernel O: out[c][n] = x[c][n] + sum_m Qhat[m][n]*KV[m][c].
// Register-tiled: thread = 4 cols x 16 channels (64 acc); per m-step
// 5 b128 LDS reads : 64 FMAs. LDS 41 KB -> 3 blocks/CU.
// grid = 8 * 256 (64-col tiles), 256 threads.
// ---------------------------------------------------------------------------
__global__ __launch_bounds__(256) void kO(
    const float* __restrict__ x, const float* __restrict__ qhat,
    const float* __restrict__ kv, float* __restrict__ out)
{
    __shared__ __align__(16) float KVs[32 * 256];  // [m][c]
    __shared__ __align__(16) float Qs [32 * 68];   // [m][j], pad 4

    const int t    = threadIdx.x;
    const int b    = blockIdx.x >> 8;
    const int tile = blockIdx.x & 255;
    const int n1   = tile << 6;

    // stage KV (linear, coalesced) and Qhat tile (per-m rows of 64)
    #pragma unroll
    for (int i = 0; i < 32; ++i)
        KVs[t + (i << 8)] = kv[b * 8192 + t + (i << 8)];
    #pragma unroll
    for (int i = 0; i < 8; ++i) {
        int f = t + (i << 8);
        int m = f >> 6, j = f & 63;
        Qs[m * 68 + j] = qhat[(size_t)(b * 32 + m) * NN + n1 + j];
    }
    __syncthreads();

    const int jq = t & 15;   // 4 cols at 4*jq
    const int cg = t >> 4;   // 16 channels at 16*cg

    float acc[4][16];
    #pragma unroll
    for (int a = 0; a < 4; ++a)
        #pragma unroll
        for (int ci = 0; ci < 16; ++ci) acc[a][ci] = 0.0f;

    #pragma unroll 8
    for (int m = 0; m < 32; ++m) {
        float4 q  = *(const float4*)&Qs[m * 68 + (jq << 2)];
        const float* kr = &KVs[m * 256 + (cg << 4)];
        float4 k0 = *(const float4*)(kr     );   // 16-lane broadcasts
        float4 k1 = *(const float4*)(kr +  4);
        float4 k2 = *(const float4*)(kr +  8);
        float4 k3 = *(const float4*)(kr + 12);
        const float kk[16] = {k0.x, k0.y, k0.z, k0.w, k1.x, k1.y, k1.z, k1.w,
                              k2.x, k2.y, k2.z, k2.w, k3.x, k3.y, k3.z, k3.w};
        const float qq[4] = {q.x, q.y, q.z, q.w};
        #pragma unroll
        for (int ci = 0; ci < 16; ++ci)
            #pragma unroll
            for (int a = 0; a < 4; ++a)
                acc[a][ci] = fmaf(qq[a], kk[ci], acc[a][ci]);
    }

    // epilogue: residual add + store, float4 per (channel, col-quad)
    const float* __restrict__ xb = x   + (size_t)b * NC * NN + n1 + (jq << 2);
    float* __restrict__       ob = out + (size_t)b * NC * NN + n1 + (jq << 2);
    #pragma unroll
    for (int ci = 0; ci < 16; ++ci) {
        const int c = (cg << 4) + ci;
        float4 xv = *(const float4*)&xb[(size_t)c * NN];
        float4 ov;
        ov.x = xv.x + acc[0][ci];
        ov.y = xv.y + acc[1][ci];
        ov.z = xv.z + acc[2][ci];
        ov.w = xv.w + acc[3][ci];
        *(float4*)&ob[(size_t)c * NN] = ov;
    }
}

// ---------------------------------------------------------------------------
// Kernel C (fallback, round-0 proven at 142 us): fused Q/den/out.
// Used only when workspace is too small for the qhat path.
// grid 512 (b, 256-col tile), 512 threads, LDS ~140 KB.
// ---------------------------------------------------------------------------
__global__ __launch_bounds__(512) void kC(
    const float* __restrict__ x, const float* __restrict__ wq,
    const float* __restrict__ bq, const float* __restrict__ kv,
    const float* __restrict__ ksum, const float* __restrict__ gamma,
    float* __restrict__ out)
{
    __shared__ __align__(16) float xs [256 * 64];  // [c][j]
    __shared__ __align__(16) float wqM[32 * 260];  // [m][c]
    __shared__ __align__(16) float Qs [32 * 68];   // [m][j]
    __shared__ __align__(16) float KVs[32 * 256];  // [m][c]
    __shared__ float ksE[32];

    const int t    = threadIdx.x;
    const int b    = blockIdx.x >> 6;
    const int tile = blockIdx.x & 63;
    const int n0   = tile << 8;
    const float* xb = x + (size_t)b * NC * NN;
    const float g = gamma[0];

    #pragma unroll
    for (int i = 0; i < 16; ++i) {
        int f = t + (i << 9);
        wqM[(f >> 8) * 260 + (f & 255)] = wq[f];
        KVs[f] = kv[(size_t)b * 8192 + f];
    }
    if (t < 32) ksE[t] = ksum[b * 32 + t] + EPSF;

    const int jsQ = t & 15;        // Q-compute: 4 j's at 4*jsQ
    const int mQ  = t >> 4;        // Q-compute: m
    const float bqm = bq[mQ];
    const int jO  = t & 63;        // out-phase: column
    const int c0O = (t >> 6) << 5; // out-phase: 32 c's

    for (int st = 0; st < 4; ++st) {
        const int n1 = n0 + (st << 6);
        __syncthreads();  // xs free (covers wqM/KVs/ksE on st=0)
        #pragma unroll
        for (int i = 0; i < 32; ++i) {
            int f = t + (i << 9);
            int c = f >> 6, j = f & 63;
            xs[f] = xb[c * NN + n1 + j];
        }
        __syncthreads();

        // --- Q compute: Q[mQ][4jsQ..+3] ---
        float qa[4] = {0.f, 0.f, 0.f, 0.f};
        #pragma unroll 4
        for (int c = 0; c < 256; c += 4) {
            float4 w  = *(const float4*)&wqM[mQ * 260 + c];
            float4 x0 = *(const float4*)&xs[(c + 0) * 64 + (jsQ << 2)];
            float4 x1 = *(const float4*)&xs[(c + 1) * 64 + (jsQ << 2)];
            float4 x2 = *(const float4*)&xs[(c + 2) * 64 + (jsQ << 2)];
            float4 x3 = *(const float4*)&xs[(c + 3) * 64 + (jsQ << 2)];
            qa[0] = fmaf(w.x, x0.x, qa[0]); qa[0] = fmaf(w.y, x1.x, qa[0]);
            qa[0] = fmaf(w.z, x2.x, qa[0]); qa[0] = fmaf(w.w, x3.x, qa[0]);
            qa[1] = fmaf(w.x, x0.y, qa[1]); qa[1] = fmaf(w.y, x1.y, qa[1]);
            qa[1] = fmaf(w.z, x2.y, qa[1]); qa[1] = fmaf(w.w, x3.y, qa[1]);
            qa[2] = fmaf(w.x, x0.z, qa[2]); qa[2] = fmaf(w.y, x1.z, qa[2]);
            qa[2] = fmaf(w.z, x2.z, qa[2]); qa[2] = fmaf(w.w, x3.z, qa[2]);
            qa[3] = fmaf(w.x, x0.w, qa[3]); qa[3] = fmaf(w.y, x1.w, qa[3]);
            qa[3] = fmaf(w.z, x2.w, qa[3]); qa[3] = fmaf(w.w, x3.w, qa[3]);
        }
        #pragma unroll
        for (int r = 0; r < 4; ++r)
            Qs[mQ * 68 + (jsQ << 2) + r] = softplusf(qa[r] + bqm);
        __syncthreads();

        // --- out phase ---
        float q[32];
        #pragma unroll
        for (int m = 0; m < 32; ++m) q[m] = Qs[m * 68 + jO];
        float den = 0.f;
        #pragma unroll
        for (int m = 0; m < 32; ++m) den = fmaf(q[m], ksE[m], den);
        const float nrm = g / den;

        #pragma unroll
        for (int cc = 0; cc < 8; ++cc) {
            const int c = c0O + (cc << 2);
            float s0 = 0.f, s1 = 0.f, s2 = 0.f, s3 = 0.f;
            #pragma unroll
            for (int m = 0; m < 32; ++m) {
                float4 kvv = *(const float4*)&KVs[m * 256 + c];  // wave-uniform
                s0 = fmaf(q[m], kvv.x, s0);
                s1 = fmaf(q[m], kvv.y, s1);
                s2 = fmaf(q[m], kvv.z, s2);
                s3 = fmaf(q[m], kvv.w, s3);
            }
            size_t base = (size_t)b * NC * NN + (size_t)c * NN + n1 + jO;
            out[base         ] = xs[(c + 0) * 64 + jO] + nrm * s0;
            out[base +     NN] = xs[(c + 1) * 64 + jO] + nrm * s1;
            out[base + 2 * NN] = xs[(c + 2) * 64 + jO] + nrm * s2;
            out[base + 3 * NN] = xs[(c + 3) * 64 + jO] + nrm * s3;
        }
    }
}

// ---------------------------------------------------------------------------
extern "C" void kernel_launch(void* const* d_in, const int* in_sizes, int n_in,
                              void* d_out, int out_size, void* d_ws, size_t ws_size,
                              hipStream_t stream)
{
    (void)in_sizes; (void)n_in; (void)out_size;
    const float* x     = (const float*)d_in[0];
    const float* wq    = (const float*)d_in[1];
    const float* bq    = (const float*)d_in[2];
    const float* wk    = (const float*)d_in[3];
    const float* bk    = (const float*)d_in[4];
    const float* wv    = (const float*)d_in[5];
    const float* bv    = (const float*)d_in[6];
    const float* gamma = (const float*)d_in[7];
    float* out = (float*)d_out;

    char* ws = (char*)d_ws;
    float* kxf  = (float*)(ws);               // 8*8192 floats = 262144 B
    float* ksum = (float*)(ws + 262144);      // 256 floats    = 1024 B
    float* kv   = (float*)(ws + 263168);      // 8*8192 floats = 262144 B
    // big region: part (kA/kR) then reused as qhat (kQ/kO) — temporally
    // disjoint, identical size 512*8192*4 = 8*32*16384*4 = 16777216 B.
    float* big  = (float*)(ws + 525312);
    const size_t need_big = 525312ull + 16777216ull;
    const int use_big = (ws_size >= need_big) ? 1 : 0;

    hipMemsetAsync(ksum, 0, 1024, stream);
    if (!use_big) hipMemsetAsync(kxf, 0, 262144, stream);

    kA<<<dim3(512), dim3(256), 0, stream>>>(x, wk, bk, big, kxf, ksum, use_big);
    if (use_big) kR<<<dim3(256), dim3(256), 0, stream>>>(big, kxf);
    kB<<<dim3(64), dim3(256), 0, stream>>>(kxf, ksum, wv, bv, kv);
    if (use_big) {
        float* qhat = big;  // part is dead after kR
        kQ<<<dim3(512), dim3(256), 0, stream>>>(x, wq, bq, ksum, gamma, qhat);
        kO<<<dim3(2048), dim3(256), 0, stream>>>(x, qhat, kv, out);
    } else {
        kC<<<dim3(512), dim3(512), 0, stream>>>(x, wq, bq, kv, ksum, gamma, out);
    }
}